// Round 10
// baseline (7740.364 us; speedup 1.0000x reference)
//
#include <hip/hip_runtime.h>

namespace {
constexpr int kB = 16, kT = 512, kIN = 16, kD = 128, kH = 256, kL = 136, kO = 32;
constexpr int kSteps = kT - 1;      // 511
constexpr int NBLK = 128;           // one block per d; fully symmetric
constexpr int NTHR = 512;
// ---- LDS layout (bytes) ----
constexpr int OFF_W3L = 0;          // fw3 frags [9][8][64][8] f16   73728
constexpr int OFF_Z1H = 73728;      // z1 planes [16][264] f16        8448
constexpr int OFF_Z1L = 82176;      //                                8448
constexpr int OFF_Z2H = 90624;      //                                8448
constexpr int OFF_Z2L = 99072;      //                                8448
constexpr int OFF_HBH = 107520;     // h planes [16][136] f16         4352
constexpr int OFF_HBL = 111872;     //                                4352
constexpr int OFF_HB  = 116224;     // h f32 [16][128]                8192
constexpr int OFF_OMS = 124416;     // [16][140] f32                  8960
constexpr int OFF_RED = 133376;     // [16][8] f32                     512
constexpr size_t LDS_BYTES = 133888;
}

typedef __attribute__((ext_vector_type(8))) _Float16 half8;
typedef __attribute__((ext_vector_type(4))) float f32x4;

__device__ __forceinline__ float softplusf(float x) {
  return fmaxf(x, 0.0f) + log1pf(expf(-fabsf(x)));
}
#define ALOAD64(p)    __hip_atomic_load((p),  __ATOMIC_RELAXED, __HIP_MEMORY_SCOPE_AGENT)
#define ASTORE64(p,v) __hip_atomic_store((p), (v), __ATOMIC_RELAXED, __HIP_MEMORY_SCOPE_AGENT)

__global__ void __launch_bounds__(256)
rde_init(const float* __restrict__ x0,
         const float* __restrict__ iw1, const float* __restrict__ ib1,
         const float* __restrict__ iw2, const float* __restrict__ ib2,
         const float* __restrict__ iw3, const float* __restrict__ ib3,
         float* __restrict__ hist) {
  __shared__ float xs[kIN];
  __shared__ __align__(16) float t1[kH];
  __shared__ __align__(16) float t2[kH];
  const int b = blockIdx.x, tid = threadIdx.x;
  if (tid < kIN) xs[tid] = x0[b*kIN + tid];
  __syncthreads();
  {
    float a = ib1[tid];
#pragma unroll
    for (int i = 0; i < kIN; ++i) a = fmaf(xs[i], iw1[tid*kIN + i], a);
    t1[tid] = softplusf(a);
  }
  __syncthreads();
  {
    const float4* wr = (const float4*)(iw2 + (size_t)tid*kH);
    float a = ib2[tid];
#pragma unroll 8
    for (int q = 0; q < kH/4; ++q) {
      float4 w = wr[q];
      a = fmaf(t1[4*q+0], w.x, a); a = fmaf(t1[4*q+1], w.y, a);
      a = fmaf(t1[4*q+2], w.z, a); a = fmaf(t1[4*q+3], w.w, a);
    }
    t2[tid] = softplusf(a);
  }
  __syncthreads();
  if (tid < kD) {
    const float4* wr = (const float4*)(iw3 + (size_t)tid*kH);
    float a = ib3[tid];
#pragma unroll 8
    for (int q = 0; q < kH/4; ++q) {
      float4 w = wr[q];
      a = fmaf(t2[4*q+0], w.x, a); a = fmaf(t2[4*q+1], w.y, a);
      a = fmaf(t2[4*q+2], w.z, a); a = fmaf(t2[4*q+3], w.w, a);
    }
    hist[(size_t)b*kD + tid] = a;
  }
}

__global__ void __launch_bounds__(NTHR)
__attribute__((amdgpu_waves_per_eu(1, 2)))
rde_scan(const float* __restrict__ lsg,
         const float* __restrict__ fw1, const float* __restrict__ fb1,
         const float* __restrict__ fw2, const float* __restrict__ fb2,
         const float* __restrict__ fw3, const float* __restrict__ fb3,
         float* __restrict__ hist, unsigned long long* partx) {
  extern __shared__ char smem[];
  _Float16* W3L  = (_Float16*)(smem + OFF_W3L);
  _Float16* z1hi = (_Float16*)(smem + OFF_Z1H);
  _Float16* z1lo = (_Float16*)(smem + OFF_Z1L);
  _Float16* z2hi = (_Float16*)(smem + OFF_Z2H);
  _Float16* z2lo = (_Float16*)(smem + OFF_Z2L);
  _Float16* hbh  = (_Float16*)(smem + OFF_HBH);
  _Float16* hbl  = (_Float16*)(smem + OFF_HBL);
  float* hb  = (float*)(smem + OFF_HB);
  float* oms = (float*)(smem + OFF_OMS);
  float* red = (float*)(smem + OFF_RED);

  const int tid  = threadIdx.x;
  const int d_own = blockIdx.x;
  const int wave = tid >> 6, lane = tid & 63;
  const int l15  = lane & 15, g = lane >> 4;

  // ---------------- prologue ----------------
  // fw3 d-shard -> LDS fp16 fragments (9 n-tiles of 16 l's; 136 real)
  for (int i = tid; i < 9*8*64; i += NTHR) {
    const int w = i >> 9, s = (i >> 6) & 7, ln = i & 63;
    const int nl = w*16 + (ln & 15), col = s*32 + (ln >> 4)*8;
    half8 hv;
    if (nl < kL) {
      const float* p = fw3 + ((size_t)d_own*kL + nl)*kH + col;
#pragma unroll
      for (int e = 0; e < 8; ++e) hv[e] = (_Float16)p[e];
    } else {
#pragma unroll
      for (int e = 0; e < 8; ++e) hv[e] = (_Float16)0.f;
    }
    *(half8*)(W3L + ((w*8 + s)*64 + ln)*8) = hv;
  }
  const float biasv = fb3[(size_t)d_own*kL + wave*16 + l15];
  const float bias8 = (wave == 7 && l15 < 8) ? fb3[(size_t)d_own*kL + 128 + l15] : 0.f;

  // fw1 fp16 B-frags in VGPR: per wave 2 n-tiles (full 256 cols chip-wide... per block)
  half8 bw1[2][4];
  float fb1v[2];
#pragma unroll
  for (int ti = 0; ti < 2; ++ti) {
    const int n = (wave*2 + ti)*16 + l15;
    fb1v[ti] = fb1[n];
#pragma unroll
    for (int kst = 0; kst < 4; ++kst) {
      const float* p = fw1 + (size_t)n*kD + kst*32 + g*8;
      half8 h;
#pragma unroll
      for (int e = 0; e < 8; ++e) h[e] = (_Float16)p[e];
      bw1[ti][kst] = h;
    }
  }
  // fw2 fp16 B-frags in VGPR: per wave 2 n-tiles x 8 ksteps (64 VGPR)
  half8 bw2[2][8];
  float fb2v[2];
#pragma unroll
  for (int ti = 0; ti < 2; ++ti) {
    const int n = (wave*2 + ti)*16 + l15;
    fb2v[ti] = fb2[n];
#pragma unroll
    for (int kst = 0; kst < 8; ++kst) {
      const float* p = fw2 + (size_t)n*kH + kst*32 + g*8;
      half8 h;
#pragma unroll
      for (int e = 0; e < 8; ++e) h[e] = (_Float16)p[e];
      bw2[ti][kst] = h;
    }
  }
  // h0 -> hb f32 + fp16 hi/lo planes (replicated full state)
  {
    const int idx = tid*4, b = idx >> 7, d = idx & 127;
    float4 h4 = *(const float4*)(hist + (size_t)b*kD + d);
    *(float4*)(hb + idx) = h4;
    float hv[4] = {h4.x, h4.y, h4.z, h4.w};
#pragma unroll
    for (int i = 0; i < 4; ++i) {
      _Float16 hh = (_Float16)hv[i];
      hbh[b*136 + d + i] = hh;
      hbl[b*136 + d + i] = (_Float16)(hv[i] - (float)hh);
    }
  }
  __syncthreads();

  // ---------------- scan ----------------
  for (int t = 0; t < kSteps; ++t) {
    const unsigned epw = (unsigned)(t + 1);

    // oms prefetch (VMEM, overlaps MFMA phases below)
#pragma unroll 2
    for (int rep = 0; rep < 2; ++rep) {
      int cc = tid + rep*512;
      if (cc < 544) {
        int bb = cc / 34, ii = cc - bb*34;
        float4 v = *(const float4*)(lsg + ((size_t)bb*kSteps + t)*kL + ii*4);
        *(float4*)(oms + bb*140 + ii*4) = v;
      }
    }

    // [A] z1 = softplus(h @ fw1^T): M=16, per wave 2 n-tiles, K=128, h hi/lo
    {
      f32x4 a0 = {fb1v[0], fb1v[0], fb1v[0], fb1v[0]};
      f32x4 a1 = {fb1v[1], fb1v[1], fb1v[1], fb1v[1]};
#pragma unroll
      for (int kst = 0; kst < 4; ++kst) {
        half8 ah = *(const half8*)(hbh + l15*136 + kst*32 + g*8);
        half8 al = *(const half8*)(hbl + l15*136 + kst*32 + g*8);
        a0 = __builtin_amdgcn_mfma_f32_16x16x32_f16(ah, bw1[0][kst], a0, 0, 0, 0);
        a0 = __builtin_amdgcn_mfma_f32_16x16x32_f16(al, bw1[0][kst], a0, 0, 0, 0);
        a1 = __builtin_amdgcn_mfma_f32_16x16x32_f16(ah, bw1[1][kst], a1, 0, 0, 0);
        a1 = __builtin_amdgcn_mfma_f32_16x16x32_f16(al, bw1[1][kst], a1, 0, 0, 0);
      }
#pragma unroll
      for (int r = 0; r < 4; ++r) {
        const int b = g*4 + r;
        float v0 = softplusf(a0[r]);
        float v1 = softplusf(a1[r]);
        _Float16 h0 = (_Float16)v0, h1 = (_Float16)v1;
        z1hi[b*264 + (wave*2+0)*16 + l15] = h0;
        z1lo[b*264 + (wave*2+0)*16 + l15] = (_Float16)(v0 - (float)h0);
        z1hi[b*264 + (wave*2+1)*16 + l15] = h1;
        z1lo[b*264 + (wave*2+1)*16 + l15] = (_Float16)(v1 - (float)h1);
      }
    }
    __syncthreads();

    // [B] z2 = softplus(z1 @ fw2^T): K=256, z1 hi/lo
    {
      f32x4 a0 = {fb2v[0], fb2v[0], fb2v[0], fb2v[0]};
      f32x4 a1 = {fb2v[1], fb2v[1], fb2v[1], fb2v[1]};
#pragma unroll
      for (int kst = 0; kst < 8; ++kst) {
        half8 ah = *(const half8*)(z1hi + l15*264 + kst*32 + g*8);
        half8 al = *(const half8*)(z1lo + l15*264 + kst*32 + g*8);
        a0 = __builtin_amdgcn_mfma_f32_16x16x32_f16(ah, bw2[0][kst], a0, 0, 0, 0);
        a0 = __builtin_amdgcn_mfma_f32_16x16x32_f16(al, bw2[0][kst], a0, 0, 0, 0);
        a1 = __builtin_amdgcn_mfma_f32_16x16x32_f16(ah, bw2[1][kst], a1, 0, 0, 0);
        a1 = __builtin_amdgcn_mfma_f32_16x16x32_f16(al, bw2[1][kst], a1, 0, 0, 0);
      }
#pragma unroll
      for (int r = 0; r < 4; ++r) {
        const int b = g*4 + r;
        float v0 = softplusf(a0[r]);
        float v1 = softplusf(a1[r]);
        _Float16 h0 = (_Float16)v0, h1 = (_Float16)v1;
        z2hi[b*264 + (wave*2+0)*16 + l15] = h0;
        z2lo[b*264 + (wave*2+0)*16 + l15] = (_Float16)(v0 - (float)h0);
        z2hi[b*264 + (wave*2+1)*16 + l15] = h1;
        z2lo[b*264 + (wave*2+1)*16 + l15] = (_Float16)(v1 - (float)h1);
      }
    }
    __syncthreads();

    // [C] z3 tile (own d, 136 l): wave w -> n-tile w; wave 7 also tile 8
    f32x4 acc = {biasv, biasv, biasv, biasv};
    f32x4 acc8 = {bias8, bias8, bias8, bias8};
#pragma unroll
    for (int s = 0; s < 8; ++s) {
      half8 ah = *(const half8*)(z2hi + l15*264 + s*32 + g*8);
      half8 al = *(const half8*)(z2lo + l15*264 + s*32 + g*8);
      half8 bh = *(const half8*)(W3L + ((wave*8 + s)*64 + lane)*8);
      acc = __builtin_amdgcn_mfma_f32_16x16x32_f16(ah, bh, acc, 0, 0, 0);
      acc = __builtin_amdgcn_mfma_f32_16x16x32_f16(al, bh, acc, 0, 0, 0);
      if (wave == 7) {
        half8 b8 = *(const half8*)(W3L + ((64 + s)*64 + lane)*8);
        acc8 = __builtin_amdgcn_mfma_f32_16x16x32_f16(ah, b8, acc8, 0, 0, 0);
        acc8 = __builtin_amdgcn_mfma_f32_16x16x32_f16(al, b8, acc8, 0, 0, 0);
      }
    }
    // [D] in-register contraction: tanh * logsig, reduce over 16 l-lanes
#pragma unroll
    for (int r = 0; r < 4; ++r) {
      const int b = g*4 + r;
      float p = tanhf(acc[r]) * oms[b*140 + wave*16 + l15];
      if (wave == 7 && l15 < 8)
        p += tanhf(acc8[r]) * oms[b*140 + 128 + l15];
      p += __shfl_xor(p, 1); p += __shfl_xor(p, 2);
      p += __shfl_xor(p, 4); p += __shfl_xor(p, 8);
      if (l15 == 0) red[b*8 + wave] = p;
    }
    __syncthreads();
    if (tid < 16) {
      float s = 0.f;
#pragma unroll
      for (int w = 0; w < 8; ++w) s += red[tid*8 + w];
      unsigned long long pk = (unsigned long long)__float_as_uint(s)
                            | ((unsigned long long)epw << 32);
      ASTORE64(partx + (size_t)tid*NBLK + d_own, pk);   // partx[b][d]
    }

    // [E] poll ALL 2048 partials (4 u64/thread, self-validating), update h
    {
      const unsigned long long* src = partx + (size_t)tid*4;
      unsigned long long q4[4];
      for (;;) {
        bool ok = true;
#pragma unroll
        for (int i = 0; i < 4; ++i) q4[i] = ALOAD64(src + i);
#pragma unroll
        for (int i = 0; i < 4; ++i) ok &= ((unsigned)(q4[i] >> 32) == epw);
        if (ok) break;
        __builtin_amdgcn_s_sleep(1);
      }
      const int idx0 = tid*4, b = idx0 >> 7, d0 = idx0 & 127;
#pragma unroll
      for (int i = 0; i < 4; ++i) {
        float hn = hb[idx0 + i] + __uint_as_float((unsigned)q4[i]);
        hb[idx0 + i] = hn;
        _Float16 hh = (_Float16)hn;
        hbh[b*136 + d0 + i] = hh;
        hbl[b*136 + d0 + i] = (_Float16)(hn - (float)hh);
      }
    }
    __syncthreads();
    // blocks 0..15 record h_{t+1} for batch row b = d_own
    if (d_own < kB && tid < kD)
      hist[((size_t)(t+1)*kB + d_own)*kD + tid] = hb[d_own*kD + tid];
  }
}

__global__ void __launch_bounds__(512)
rde_readout(const float* __restrict__ hist, const float* __restrict__ rw,
            const float* __restrict__ rb, float* __restrict__ out) {
  const int t = blockIdx.x, tid = threadIdx.x;
  const int b = tid >> 5, o = tid & 31;
  const float4* hr = (const float4*)(hist + ((size_t)t*kB + b)*kD);
  const float4* wr = (const float4*)(rw + (size_t)o*kD);
  float a = rb[o];
#pragma unroll 8
  for (int q = 0; q < kD/4; ++q) {
    float4 h4 = hr[q], w4 = wr[q];
    a = fmaf(h4.x,w4.x,a); a = fmaf(h4.y,w4.y,a);
    a = fmaf(h4.z,w4.z,a); a = fmaf(h4.w,w4.w,a);
  }
  out[((size_t)b*kT + t)*kO + o] = a;
}

extern "C" void kernel_launch(void* const* d_in, const int* in_sizes, int n_in,
                              void* d_out, int out_size, void* d_ws, size_t ws_size,
                              hipStream_t stream) {
  const float* x0  = (const float*)d_in[0];
  const float* lsg = (const float*)d_in[1];
  const float* iw1 = (const float*)d_in[2];
  const float* ib1 = (const float*)d_in[3];
  const float* iw2 = (const float*)d_in[4];
  const float* ib2 = (const float*)d_in[5];
  const float* iw3 = (const float*)d_in[6];
  const float* ib3 = (const float*)d_in[7];
  const float* fw1 = (const float*)d_in[8];
  const float* fb1 = (const float*)d_in[9];
  const float* fw2 = (const float*)d_in[10];
  const float* fb2 = (const float*)d_in[11];
  const float* fw3 = (const float*)d_in[12];
  const float* fb3 = (const float*)d_in[13];
  const float* rw  = (const float*)d_in[14];
  const float* rb  = (const float*)d_in[15];
  float* out = (float*)d_out;

  float* hist = (float*)d_ws;                                  // 512*16*128 f32
  unsigned long long* partx =
      (unsigned long long*)(hist + (size_t)kT*kB*kD);          // [16][128] u64

  hipMemsetAsync(partx, 0, (size_t)kB*NBLK*8, stream);
  hipFuncSetAttribute((const void*)rde_scan,
                      hipFuncAttributeMaxDynamicSharedMemorySize, (int)LDS_BYTES);

  rde_init<<<kB, 256, 0, stream>>>(x0, iw1, ib1, iw2, ib2, iw3, ib3, hist);

  rde_scan<<<NBLK, NTHR, LDS_BYTES, stream>>>(
      lsg, fw1, fb1, fw2, fb2, fw3, fb3, hist, partx);

  rde_readout<<<kT, 512, 0, stream>>>(hist, rw, rb, out);
}

// Round 11
// 7682.159 us; speedup vs baseline: 1.0076x; 1.0076x over previous
//
#include <hip/hip_runtime.h>

namespace {
constexpr int kB = 16, kT = 512, kIN = 16, kD = 128, kH = 256, kL = 136, kO = 32;
constexpr int kSteps = kT - 1;      // 511
constexpr int NBLK = 128;           // one symmetric block per d
constexpr int NTHR = 512;
// ---- LDS layout (bytes) ----
constexpr int OFF_W3L = 0;          // fw3 frags [9][8][64][8] f16   73728
constexpr int OFF_Z1H = 73728;      // z1 planes [16][264] f16        8448
constexpr int OFF_Z1L = 82176;      //                                8448
constexpr int OFF_Z2H = 90624;      //                                8448
constexpr int OFF_Z2L = 99072;      //                                8448
constexpr int OFF_HBH = 107520;     // h planes [16][136] f16         4352
constexpr int OFF_HBL = 111872;     //                                4352
constexpr int OFF_HB  = 116224;     // h f32 [16][128]                8192
constexpr int OFF_OMS = 124416;     // [16][140] f32                  8960
constexpr int OFF_RED = 133376;     // [16][8] f32                     512
constexpr size_t LDS_BYTES = 133888;
constexpr int N_FW1P = 16*4*64*8;   // 32768 fp16 (fragment-ordered fw1)
constexpr int N_FW2P = 16*8*64*8;   // 65536 fp16
}

typedef __attribute__((ext_vector_type(8))) _Float16 half8;
typedef __attribute__((ext_vector_type(4))) float f32x4;

__device__ __forceinline__ float softplusf(float x) {
  return fmaxf(x, 0.0f) + log1pf(expf(-fabsf(x)));
}
#define ALOAD64(p)    __hip_atomic_load((p),  __ATOMIC_RELAXED, __HIP_MEMORY_SCOPE_AGENT)
#define ASTORE64(p,v) __hip_atomic_store((p), (v), __ATOMIC_RELAXED, __HIP_MEMORY_SCOPE_AGENT)

// pack fw1/fw2 into fragment-ordered fp16: value = w[(nt*16+(lane&15))*K + kst*32 + (lane>>4)*8 + e]
__global__ void __launch_bounds__(256)
rde_prep(const float* __restrict__ fw1, const float* __restrict__ fw2,
         _Float16* __restrict__ fw1p, _Float16* __restrict__ fw2p) {
  int idx = blockIdx.x * 256 + threadIdx.x;
  if (idx < N_FW1P) {
    int e = idx & 7, ln = (idx >> 3) & 63, kst = (idx >> 9) & 3, nt = idx >> 11;
    fw1p[idx] = (_Float16)fw1[(size_t)(nt*16 + (ln & 15))*kD + kst*32 + (ln >> 4)*8 + e];
  } else {
    int j = idx - N_FW1P;
    if (j < N_FW2P) {
      int e = j & 7, ln = (j >> 3) & 63, kst = (j >> 9) & 7, nt = j >> 12;
      fw2p[j] = (_Float16)fw2[(size_t)(nt*16 + (ln & 15))*kH + kst*32 + (ln >> 4)*8 + e];
    }
  }
}

__global__ void __launch_bounds__(256)
rde_init(const float* __restrict__ x0,
         const float* __restrict__ iw1, const float* __restrict__ ib1,
         const float* __restrict__ iw2, const float* __restrict__ ib2,
         const float* __restrict__ iw3, const float* __restrict__ ib3,
         float* __restrict__ hist) {
  __shared__ float xs[kIN];
  __shared__ __align__(16) float t1[kH];
  __shared__ __align__(16) float t2[kH];
  const int b = blockIdx.x, tid = threadIdx.x;
  if (tid < kIN) xs[tid] = x0[b*kIN + tid];
  __syncthreads();
  {
    float a = ib1[tid];
#pragma unroll
    for (int i = 0; i < kIN; ++i) a = fmaf(xs[i], iw1[tid*kIN + i], a);
    t1[tid] = softplusf(a);
  }
  __syncthreads();
  {
    const float4* wr = (const float4*)(iw2 + (size_t)tid*kH);
    float a = ib2[tid];
#pragma unroll 8
    for (int q = 0; q < kH/4; ++q) {
      float4 w = wr[q];
      a = fmaf(t1[4*q+0], w.x, a); a = fmaf(t1[4*q+1], w.y, a);
      a = fmaf(t1[4*q+2], w.z, a); a = fmaf(t1[4*q+3], w.w, a);
    }
    t2[tid] = softplusf(a);
  }
  __syncthreads();
  if (tid < kD) {
    const float4* wr = (const float4*)(iw3 + (size_t)tid*kH);
    float a = ib3[tid];
#pragma unroll 8
    for (int q = 0; q < kH/4; ++q) {
      float4 w = wr[q];
      a = fmaf(t2[4*q+0], w.x, a); a = fmaf(t2[4*q+1], w.y, a);
      a = fmaf(t2[4*q+2], w.z, a); a = fmaf(t2[4*q+3], w.w, a);
    }
    hist[(size_t)b*kD + tid] = a;
  }
}

__global__ void __launch_bounds__(NTHR)
rde_scan(const float* __restrict__ lsg,
         const _Float16* __restrict__ fw1p, const float* __restrict__ fb1,
         const _Float16* __restrict__ fw2p, const float* __restrict__ fb2,
         const float* __restrict__ fw3, const float* __restrict__ fb3,
         float* __restrict__ hist, unsigned long long* partx) {
  extern __shared__ char smem[];
  _Float16* W3L  = (_Float16*)(smem + OFF_W3L);
  _Float16* z1hi = (_Float16*)(smem + OFF_Z1H);
  _Float16* z1lo = (_Float16*)(smem + OFF_Z1L);
  _Float16* z2hi = (_Float16*)(smem + OFF_Z2H);
  _Float16* z2lo = (_Float16*)(smem + OFF_Z2L);
  _Float16* hbh  = (_Float16*)(smem + OFF_HBH);
  _Float16* hbl  = (_Float16*)(smem + OFF_HBL);
  float* hb  = (float*)(smem + OFF_HB);
  float* oms = (float*)(smem + OFF_OMS);
  float* red = (float*)(smem + OFF_RED);

  const int tid  = threadIdx.x;
  const int d_own = blockIdx.x;
  const int wave = tid >> 6, lane = tid & 63;
  const int l15  = lane & 15, g = lane >> 4;
  const int t0 = wave*2, t1w = wave*2 + 1;    // this wave's two n-tiles

  // ---------------- prologue ----------------
  // fw3 d-shard -> LDS fp16 fragments (9 n-tiles; 136 real l's)
  for (int i = tid; i < 9*8*64; i += NTHR) {
    const int w = i >> 9, s = (i >> 6) & 7, ln = i & 63;
    const int nl = w*16 + (ln & 15), col = s*32 + (ln >> 4)*8;
    half8 hv;
    if (nl < kL) {
      const float* p = fw3 + ((size_t)d_own*kL + nl)*kH + col;
#pragma unroll
      for (int e = 0; e < 8; ++e) hv[e] = (_Float16)p[e];
    } else {
#pragma unroll
      for (int e = 0; e < 8; ++e) hv[e] = (_Float16)0.f;
    }
    *(half8*)(W3L + ((w*8 + s)*64 + ln)*8) = hv;
  }
  const float biasv = fb3[(size_t)d_own*kL + wave*16 + l15];
  const float bias8 = (wave == 7 && l15 < 8) ? fb3[(size_t)d_own*kL + 128 + l15] : 0.f;
  const float fb1v0 = fb1[t0*16 + l15], fb1v1 = fb1[t1w*16 + l15];
  const float fb2v0 = fb2[t0*16 + l15], fb2v1 = fb2[t1w*16 + l15];

  // h0 -> hb f32 + fp16 hi/lo planes (replicated full state)
  {
    const int idx = tid*4, b = idx >> 7, d = idx & 127;
    float4 h4 = *(const float4*)(hist + (size_t)b*kD + d);
    *(float4*)(hb + idx) = h4;
    float hv[4] = {h4.x, h4.y, h4.z, h4.w};
#pragma unroll
    for (int i = 0; i < 4; ++i) {
      _Float16 hh = (_Float16)hv[i];
      hbh[b*136 + d + i] = hh;
      hbl[b*136 + d + i] = (_Float16)(hv[i] - (float)hh);
    }
  }
  __syncthreads();

  // ---------------- scan ----------------
  for (int t = 0; t < kSteps; ++t) {
    const unsigned epw = (unsigned)(t + 1);

    // oms prefetch (VMEM, overlaps MFMA phases below)
#pragma unroll 2
    for (int rep = 0; rep < 2; ++rep) {
      int cc = tid + rep*512;
      if (cc < 544) {
        int bb = cc / 34, ii = cc - bb*34;
        float4 v = *(const float4*)(lsg + ((size_t)bb*kSteps + t)*kL + ii*4);
        *(float4*)(oms + bb*140 + ii*4) = v;
      }
    }

    // [A] z1 = softplus(h @ fw1^T): weights streamed from L2 (transient regs)
    {
      f32x4 a0 = {fb1v0, fb1v0, fb1v0, fb1v0};
      f32x4 a1 = {fb1v1, fb1v1, fb1v1, fb1v1};
      half8 w0[4], w1[4];
#pragma unroll
      for (int kst = 0; kst < 4; ++kst) {
        w0[kst] = *(const half8*)(fw1p + (size_t)((t0 *4 + kst)*64 + lane)*8);
        w1[kst] = *(const half8*)(fw1p + (size_t)((t1w*4 + kst)*64 + lane)*8);
      }
#pragma unroll
      for (int kst = 0; kst < 4; ++kst) {
        half8 ah = *(const half8*)(hbh + l15*136 + kst*32 + g*8);
        half8 al = *(const half8*)(hbl + l15*136 + kst*32 + g*8);
        a0 = __builtin_amdgcn_mfma_f32_16x16x32_f16(ah, w0[kst], a0, 0, 0, 0);
        a0 = __builtin_amdgcn_mfma_f32_16x16x32_f16(al, w0[kst], a0, 0, 0, 0);
        a1 = __builtin_amdgcn_mfma_f32_16x16x32_f16(ah, w1[kst], a1, 0, 0, 0);
        a1 = __builtin_amdgcn_mfma_f32_16x16x32_f16(al, w1[kst], a1, 0, 0, 0);
      }
#pragma unroll
      for (int r = 0; r < 4; ++r) {
        const int b = g*4 + r;
        float v0 = softplusf(a0[r]);
        float v1 = softplusf(a1[r]);
        _Float16 h0 = (_Float16)v0, h1 = (_Float16)v1;
        z1hi[b*264 + t0*16 + l15] = h0;
        z1lo[b*264 + t0*16 + l15] = (_Float16)(v0 - (float)h0);
        z1hi[b*264 + t1w*16 + l15] = h1;
        z1lo[b*264 + t1w*16 + l15] = (_Float16)(v1 - (float)h1);
      }
    }
    __syncthreads();

    // [B] z2 = softplus(z1 @ fw2^T): K=256, weights streamed in 2 chunks
    {
      f32x4 a0 = {fb2v0, fb2v0, fb2v0, fb2v0};
      f32x4 a1 = {fb2v1, fb2v1, fb2v1, fb2v1};
#pragma unroll
      for (int half = 0; half < 2; ++half) {
        half8 w0[4], w1[4];
#pragma unroll
        for (int kq = 0; kq < 4; ++kq) {
          const int kst = half*4 + kq;
          w0[kq] = *(const half8*)(fw2p + (size_t)((t0 *8 + kst)*64 + lane)*8);
          w1[kq] = *(const half8*)(fw2p + (size_t)((t1w*8 + kst)*64 + lane)*8);
        }
#pragma unroll
        for (int kq = 0; kq < 4; ++kq) {
          const int kst = half*4 + kq;
          half8 ah = *(const half8*)(z1hi + l15*264 + kst*32 + g*8);
          half8 al = *(const half8*)(z1lo + l15*264 + kst*32 + g*8);
          a0 = __builtin_amdgcn_mfma_f32_16x16x32_f16(ah, w0[kq], a0, 0, 0, 0);
          a0 = __builtin_amdgcn_mfma_f32_16x16x32_f16(al, w0[kq], a0, 0, 0, 0);
          a1 = __builtin_amdgcn_mfma_f32_16x16x32_f16(ah, w1[kq], a1, 0, 0, 0);
          a1 = __builtin_amdgcn_mfma_f32_16x16x32_f16(al, w1[kq], a1, 0, 0, 0);
        }
      }
#pragma unroll
      for (int r = 0; r < 4; ++r) {
        const int b = g*4 + r;
        float v0 = softplusf(a0[r]);
        float v1 = softplusf(a1[r]);
        _Float16 h0 = (_Float16)v0, h1 = (_Float16)v1;
        z2hi[b*264 + t0*16 + l15] = h0;
        z2lo[b*264 + t0*16 + l15] = (_Float16)(v0 - (float)h0);
        z2hi[b*264 + t1w*16 + l15] = h1;
        z2lo[b*264 + t1w*16 + l15] = (_Float16)(v1 - (float)h1);
      }
    }
    __syncthreads();

    // [C] z3 (own d, 136 l): wave w -> n-tile w; wave 7 also tile 8
    f32x4 acc = {biasv, biasv, biasv, biasv};
    f32x4 acc8 = {bias8, bias8, bias8, bias8};
#pragma unroll
    for (int s = 0; s < 8; ++s) {
      half8 ah = *(const half8*)(z2hi + l15*264 + s*32 + g*8);
      half8 al = *(const half8*)(z2lo + l15*264 + s*32 + g*8);
      half8 bh = *(const half8*)(W3L + ((wave*8 + s)*64 + lane)*8);
      acc = __builtin_amdgcn_mfma_f32_16x16x32_f16(ah, bh, acc, 0, 0, 0);
      acc = __builtin_amdgcn_mfma_f32_16x16x32_f16(al, bh, acc, 0, 0, 0);
      if (wave == 7) {
        half8 b8 = *(const half8*)(W3L + ((64 + s)*64 + lane)*8);
        acc8 = __builtin_amdgcn_mfma_f32_16x16x32_f16(ah, b8, acc8, 0, 0, 0);
        acc8 = __builtin_amdgcn_mfma_f32_16x16x32_f16(al, b8, acc8, 0, 0, 0);
      }
    }
    // [D] in-register contraction: tanh * logsig, reduce over 16 l-lanes
#pragma unroll
    for (int r = 0; r < 4; ++r) {
      const int b = g*4 + r;
      float p = tanhf(acc[r]) * oms[b*140 + wave*16 + l15];
      if (wave == 7 && l15 < 8)
        p += tanhf(acc8[r]) * oms[b*140 + 128 + l15];
      p += __shfl_xor(p, 1); p += __shfl_xor(p, 2);
      p += __shfl_xor(p, 4); p += __shfl_xor(p, 8);
      if (l15 == 0) red[b*8 + wave] = p;
    }
    __syncthreads();
    if (tid < 16) {
      float s = 0.f;
#pragma unroll
      for (int w = 0; w < 8; ++w) s += red[tid*8 + w];
      unsigned long long pk = (unsigned long long)__float_as_uint(s)
                            | ((unsigned long long)epw << 32);
      ASTORE64(partx + (size_t)tid*NBLK + d_own, pk);   // partx[b][d]
    }

    // [E] the ONE exchange: poll all 2048 partials (4/thread, batched), update h
    {
      const unsigned long long* src = partx + (size_t)tid*4;
      unsigned long long q4[4];
      for (;;) {
        bool ok = true;
#pragma unroll
        for (int i = 0; i < 4; ++i) q4[i] = ALOAD64(src + i);
#pragma unroll
        for (int i = 0; i < 4; ++i) ok &= ((unsigned)(q4[i] >> 32) == epw);
        if (ok) break;
        __builtin_amdgcn_s_sleep(2);
      }
      const int idx0 = tid*4, b = idx0 >> 7, d0 = idx0 & 127;
#pragma unroll
      for (int i = 0; i < 4; ++i) {
        float hn = hb[idx0 + i] + __uint_as_float((unsigned)q4[i]);
        hb[idx0 + i] = hn;
        _Float16 hh = (_Float16)hn;
        hbh[b*136 + d0 + i] = hh;
        hbl[b*136 + d0 + i] = (_Float16)(hn - (float)hh);
      }
    }
    __syncthreads();
    // blocks 0..15 record h_{t+1} for batch row b = d_own
    if (d_own < kB && tid < kD)
      hist[((size_t)(t+1)*kB + d_own)*kD + tid] = hb[d_own*kD + tid];
  }
}

__global__ void __launch_bounds__(512)
rde_readout(const float* __restrict__ hist, const float* __restrict__ rw,
            const float* __restrict__ rb, float* __restrict__ out) {
  const int t = blockIdx.x, tid = threadIdx.x;
  const int b = tid >> 5, o = tid & 31;
  const float4* hr = (const float4*)(hist + ((size_t)t*kB + b)*kD);
  const float4* wr = (const float4*)(rw + (size_t)o*kD);
  float a = rb[o];
#pragma unroll 8
  for (int q = 0; q < kD/4; ++q) {
    float4 h4 = hr[q], w4 = wr[q];
    a = fmaf(h4.x,w4.x,a); a = fmaf(h4.y,w4.y,a);
    a = fmaf(h4.z,w4.z,a); a = fmaf(h4.w,w4.w,a);
  }
  out[((size_t)b*kT + t)*kO + o] = a;
}

extern "C" void kernel_launch(void* const* d_in, const int* in_sizes, int n_in,
                              void* d_out, int out_size, void* d_ws, size_t ws_size,
                              hipStream_t stream) {
  const float* x0  = (const float*)d_in[0];
  const float* lsg = (const float*)d_in[1];
  const float* iw1 = (const float*)d_in[2];
  const float* ib1 = (const float*)d_in[3];
  const float* iw2 = (const float*)d_in[4];
  const float* ib2 = (const float*)d_in[5];
  const float* iw3 = (const float*)d_in[6];
  const float* ib3 = (const float*)d_in[7];
  const float* fw1 = (const float*)d_in[8];
  const float* fb1 = (const float*)d_in[9];
  const float* fw2 = (const float*)d_in[10];
  const float* fb2 = (const float*)d_in[11];
  const float* fw3 = (const float*)d_in[12];
  const float* fb3 = (const float*)d_in[13];
  const float* rw  = (const float*)d_in[14];
  const float* rb  = (const float*)d_in[15];
  float* out = (float*)d_out;

  float* hist = (float*)d_ws;                                  // 512*16*128 f32
  unsigned long long* partx =
      (unsigned long long*)(hist + (size_t)kT*kB*kD);          // [16][128] u64
  _Float16* fw1p = (_Float16*)(partx + (size_t)kB*NBLK);       // 32768 f16
  _Float16* fw2p = fw1p + N_FW1P;                              // 65536 f16

  hipMemsetAsync(partx, 0, (size_t)kB*NBLK*8, stream);
  hipFuncSetAttribute((const void*)rde_scan,
                      hipFuncAttributeMaxDynamicSharedMemorySize, (int)LDS_BYTES);

  rde_prep<<<(N_FW1P + N_FW2P + 255)/256, 256, 0, stream>>>(fw1, fw2, fw1p, fw2p);
  rde_init<<<kB, 256, 0, stream>>>(x0, iw1, ib1, iw2, ib2, iw3, ib3, hist);

  rde_scan<<<NBLK, NTHR, LDS_BYTES, stream>>>(
      lsg, fw1p, fb1, fw2p, fb2, fw3, fb3, hist, partx);

  rde_readout<<<kT, 512, 0, stream>>>(hist, rw, rb, out);
}